// Round 13
// baseline (165.857 us; speedup 1.0000x reference)
//
#include <hip/hip_runtime.h>
#include <hip/hip_bf16.h>

#define BB 16
#define SS 128
#define DD 256
#define KK 12
#define NN 128
#define WW 116

#define NPRED (BB * WW * KK * DD)   // 5,701,632 floats
#define NLAT  (BB * SS * DD)        // 524,288 floats

typedef __attribute__((ext_vector_type(8))) short short8;
typedef __attribute__((ext_vector_type(4))) float f32x4;

// XOR swizzle for [16][512B] bf16 LDS tiles (G4).
__device__ __forceinline__ int swz(int byte_off, int row) {
    return byte_off ^ ((row & 7) << 4);
}

// ---------------------------------------------------------------------------
// Kernel 0: one-shot fp32 -> (hi,lo) bf16 split of pred and latent into ws.
// Memory-bound, fully parallel. Removes ALL conversion VALU from the hot loop
// (R10: cvt_hilo8 sat in the load->MFMA dependency chain; VALUBusy 8% was
// exactly this work while everything else idled).
// ---------------------------------------------------------------------------
__global__ __launch_bounds__(256)
void cvt_split(const float* __restrict__ pred, const float* __restrict__ latent,
               ushort* __restrict__ Phi, ushort* __restrict__ Plo,
               ushort* __restrict__ Lhi, ushort* __restrict__ Llo) {
    const int g  = blockIdx.x * 256 + threadIdx.x;
    const int i4 = g * 4;
    const float* src; ushort* dh; ushort* dl; int off;
    if (i4 < NPRED)      { src = pred;   dh = Phi; dl = Plo; off = i4; }
    else                 { off = i4 - NPRED;
                           if (off >= NLAT) return;
                           src = latent; dh = Lhi; dl = Llo; }
    const float4 v = *reinterpret_cast<const float4*>(src + off);
    float x[4] = {v.x, v.y, v.z, v.w};
    ushort h[4], l[4];
#pragma unroll
    for (int i = 0; i < 4; ++i) {
        __hip_bfloat16 hb = __float2bfloat16(x[i]);
        float hf = __bfloat162float(hb);
        __hip_bfloat16 lb = __float2bfloat16(x[i] - hf);
        h[i] = __builtin_bit_cast(ushort, hb);
        l[i] = __builtin_bit_cast(ushort, lb);
    }
    ushort4 hv; hv.x = h[0]; hv.y = h[1]; hv.z = h[2]; hv.w = h[3];
    ushort4 lv; lv.x = l[0]; lv.y = l[1]; lv.z = l[2]; lv.w = l[3];
    *reinterpret_cast<ushort4*>(dh + off) = hv;
    *reinterpret_cast<ushort4*>(dl + off) = lv;
}

// ---------------------------------------------------------------------------
// Kernel 1: one 256-thread block per (b,w). Negative scores via 3-pass
// bf16-split MFMA; A (pred hi/lo) staged in LDS swizzled; B (gathered latent
// hi/lo) loaded straight as short8 with a 2-deep register double-buffer.
// Hot loop has ZERO conversion VALU.
// ---------------------------------------------------------------------------
__global__ __launch_bounds__(256, 4)
void cpc_main(const ushort* __restrict__ Phi, const ushort* __restrict__ Plo,
              const ushort* __restrict__ Lhi, const ushort* __restrict__ Llo,
              const float* __restrict__ pred,
              const float* __restrict__ latent,
              const int* __restrict__ bidx,
              const int* __restrict__ sidx,
              float* __restrict__ out) {
    const int wg = blockIdx.x;          // b*W + w
    const int b  = wg / WW;
    const int w  = wg - b * WW;
    const int t  = threadIdx.x;

    __shared__ ushort Ahi[16 * DD];     // 8 KB, [16][256] bf16 swizzled
    __shared__ ushort Alo[16 * DD];     // 8 KB
    __shared__ float sc[KK][NN + 1];    // 6.2 KB
    __shared__ float posv[KK];

    // ---- stage A = pred hi/lo tile (pure copy, no cvt) ----
    if (t < 96) {                       // 12 rows x 8 segs of 32 els
        const int r = t >> 3, seg = t & 7;
        const ushort* sh = Phi + ((size_t)wg * KK + r) * DD + seg * 32;
        const ushort* sl = Plo + ((size_t)wg * KK + r) * DD + seg * 32;
#pragma unroll
        for (int c = 0; c < 4; ++c) {   // 4 chunks of 8 els (16B)
            const short8 h = *reinterpret_cast<const short8*>(sh + c * 8);
            const short8 l = *reinterpret_cast<const short8*>(sl + c * 8);
            const int byte = r * 512 + seg * 64 + c * 16;
            *reinterpret_cast<short8*>((char*)Ahi + swz(byte, r)) = h;
            *reinterpret_cast<short8*>((char*)Alo + swz(byte, r)) = l;
        }
    } else if (t < 128) {               // zero pad rows 12..15
        const int u = t - 96;
        const int r = 12 + (u >> 3), seg = u & 7;
        const short8 z = {0, 0, 0, 0, 0, 0, 0, 0};
#pragma unroll
        for (int c = 0; c < 4; ++c) {
            const int byte = r * 512 + seg * 64 + c * 16;
            *reinterpret_cast<short8*>((char*)Ahi + swz(byte, r)) = z;
            *reinterpret_cast<short8*>((char*)Alo + swz(byte, r)) = z;
        }
    }

    // ---- per-lane gather setup ----
    const int wv   = t >> 6;
    const int lane = t & 63;
    const int lr   = lane & 15;         // B col n-in-tile / D col
    const int lg   = lane >> 4;         // k-group 0..3
    const int n0 = wv * 32 + lr;
    const int n1 = n0 + 16;
    const int i0 = (b * NN + n0) * WW + w;
    const int i1 = (b * NN + n1) * WW + w;
    const int ext0 = ((sidx[i0] + w) & (SS - 1)) + bidx[i0] * SS;
    const int ext1 = ((sidx[i1] + w) & (SS - 1)) + bidx[i1] * SS;
    const ushort* __restrict__ L0h = Lhi + (size_t)ext0 * DD + lg * 8;
    const ushort* __restrict__ L0l = Llo + (size_t)ext0 * DD + lg * 8;
    const ushort* __restrict__ L1h = Lhi + (size_t)ext1 * DD + lg * 8;
    const ushort* __restrict__ L1l = Llo + (size_t)ext1 * DD + lg * 8;

    __syncthreads();

    // ---- MFMA K-loop, 2-deep register double-buffer (named vars) ----
    f32x4 acc0 = {0.f, 0.f, 0.f, 0.f};
    f32x4 acc1 = {0.f, 0.f, 0.f, 0.f};
    short8 ch0 = *reinterpret_cast<const short8*>(L0h);
    short8 cl0 = *reinterpret_cast<const short8*>(L0l);
    short8 ch1 = *reinterpret_cast<const short8*>(L1h);
    short8 cl1 = *reinterpret_cast<const short8*>(L1l);
    const int abyte = lr * 512 + lg * 16;
#pragma unroll
    for (int ks = 0; ks < 8; ++ks) {
        short8 nh0, nl0, nh1, nl1;
        if (ks < 7) {                   // prefetch next step before MFMAs
            nh0 = *reinterpret_cast<const short8*>(L0h + (ks + 1) * 32);
            nl0 = *reinterpret_cast<const short8*>(L0l + (ks + 1) * 32);
            nh1 = *reinterpret_cast<const short8*>(L1h + (ks + 1) * 32);
            nl1 = *reinterpret_cast<const short8*>(L1l + (ks + 1) * 32);
        }
        const short8 ah = *reinterpret_cast<const short8*>(
            (const char*)Ahi + swz(abyte + ks * 64, lr));
        const short8 al = *reinterpret_cast<const short8*>(
            (const char*)Alo + swz(abyte + ks * 64, lr));
        acc0 = __builtin_amdgcn_mfma_f32_16x16x32_bf16(ah, ch0, acc0, 0, 0, 0);
        acc1 = __builtin_amdgcn_mfma_f32_16x16x32_bf16(ah, ch1, acc1, 0, 0, 0);
        acc0 = __builtin_amdgcn_mfma_f32_16x16x32_bf16(ah, cl0, acc0, 0, 0, 0);
        acc1 = __builtin_amdgcn_mfma_f32_16x16x32_bf16(ah, cl1, acc1, 0, 0, 0);
        acc0 = __builtin_amdgcn_mfma_f32_16x16x32_bf16(al, ch0, acc0, 0, 0, 0);
        acc1 = __builtin_amdgcn_mfma_f32_16x16x32_bf16(al, ch1, acc1, 0, 0, 0);
        ch0 = nh0; cl0 = nl0; ch1 = nh1; cl1 = nl1;
    }

    // ---- scores -> LDS. D layout: col=lane&15, row=(lane>>4)*4+reg ----
    constexpr float inv_d = 1.0f / DD;
    const int krow = lg * 4;
    if (krow < KK) {
#pragma unroll
        for (int r = 0; r < 4; ++r) {
            sc[krow + r][n0] = acc0[r] * inv_d;
            sc[krow + r][n1] = acc1[r] * inv_d;
        }
    }

    // ---- positive scores, fp32 VALU (exact) ----
    if (t < 96) {
        const int k = t >> 3, g = t & 7;
        const float* pr = pred + ((size_t)wg * KK + k) * DD + g * 32;
        const float* lrow = latent + ((size_t)b * SS + (w + k + 1)) * DD + g * 32;
        float s = 0.f;
#pragma unroll
        for (int d = 0; d < 32; d += 4) {
            const float4 pv = *reinterpret_cast<const float4*>(pr + d);
            const float4 lv = *reinterpret_cast<const float4*>(lrow + d);
            s = fmaf(pv.x, lv.x, s); s = fmaf(pv.y, lv.y, s);
            s = fmaf(pv.z, lv.z, s); s = fmaf(pv.w, lv.w, s);
        }
        s += __shfl_xor(s, 1);
        s += __shfl_xor(s, 2);
        s += __shfl_xor(s, 4);
        if (g == 0) posv[k] = s * inv_d;
    }
    __syncthreads();

    // ---- logsumexp(129) + argmax==0 per k; 8 lanes per k ----
    if (t < 96) {
        const int k = t >> 3, g = t & 7;
        const float p = posv[k];
        float v[16];
        float m = p;
#pragma unroll
        for (int j = 0; j < 16; ++j) {
            v[j] = sc[k][j * 8 + g];
            m = fmaxf(m, v[j]);
        }
        m = fmaxf(m, __shfl_xor(m, 1));
        m = fmaxf(m, __shfl_xor(m, 2));
        m = fmaxf(m, __shfl_xor(m, 4));
        float sum = (g == 0) ? __expf(p - m) : 0.f;
#pragma unroll
        for (int j = 0; j < 16; ++j) sum += __expf(v[j] - m);
        sum += __shfl_xor(sum, 1);
        sum += __shfl_xor(sum, 2);
        sum += __shfl_xor(sum, 4);
        if (g == 0) {
            constexpr float inv_bw = 1.0f / (BB * WW);
            const float lse = m + __logf(sum);
            atomicAdd(&out[k], (lse - p) * inv_bw);
            atomicAdd(&out[KK + k], (p >= m) ? inv_bw : 0.f);
        }
    }
}

extern "C" void kernel_launch(void* const* d_in, const int* in_sizes, int n_in,
                              void* d_out, int out_size, void* d_ws, size_t ws_size,
                              hipStream_t stream) {
    const float* pred   = (const float*)d_in[0];
    const float* latent = (const float*)d_in[1];
    const int*   bidx   = (const int*)d_in[2];
    const int*   sidx   = (const int*)d_in[3];
    float* out = (float*)d_out;

    // ws layout (bytes): Phi | Plo | Lhi | Llo  (all 16B-aligned)
    ushort* Phi = (ushort*)d_ws;
    ushort* Plo = Phi + NPRED;
    ushort* Lhi = Plo + NPRED;
    ushort* Llo = Lhi + NLAT;

    hipMemsetAsync(out, 0, 2 * KK * sizeof(float), stream);
    const int ncvt = (NPRED + NLAT) / 4;
    cvt_split<<<(ncvt + 255) / 256, 256, 0, stream>>>(pred, latent, Phi, Plo, Lhi, Llo);
    cpc_main<<<BB * WW, 256, 0, stream>>>(Phi, Plo, Lhi, Llo,
                                          pred, latent, bidx, sidx, out);
}